// Round 1
// baseline (386.706 us; speedup 1.0000x reference)
//
#include <hip/hip_runtime.h>

#define NN 50000
#define NE 800000
#define HID 128

static __device__ __forceinline__ float lrelu(float x) { return x > 0.f ? x : 0.01f * x; }

// ---------------- degree / norm ----------------
__global__ void deg_kernel(const int* __restrict__ src, const int* __restrict__ dst,
                           int* __restrict__ deg_out, int* __restrict__ deg_in, int E) {
    int e = blockIdx.x * blockDim.x + threadIdx.x;
    if (e < E) {
        atomicAdd(&deg_out[src[e]], 1);
        atomicAdd(&deg_in[dst[e]], 1);
    }
}

__global__ void norm_kernel(const int* __restrict__ deg_out, const int* __restrict__ deg_in,
                            float* __restrict__ norm_out, float* __restrict__ norm_in, int n) {
    int i = blockIdx.x * blockDim.x + threadIdx.x;
    if (i < n) {
        norm_out[i] = rsqrtf((float)max(deg_out[i], 1));
        norm_in[i]  = rsqrtf((float)max(deg_in[i], 1));
    }
}

// ---------------- prefix scan (3 kernels) ----------------
__global__ void scan1(const int* __restrict__ deg, int* __restrict__ excl,
                      int* __restrict__ bsums, int n) {
    __shared__ int ws[16];
    int t = threadIdx.x;
    int i = blockIdx.x * 1024 + t;
    int v = (i < n) ? deg[i] : 0;
    int x = v;
    #pragma unroll
    for (int o = 1; o < 64; o <<= 1) {
        int y = __shfl_up(x, o, 64);
        if ((t & 63) >= o) x += y;
    }
    if ((t & 63) == 63) ws[t >> 6] = x;
    __syncthreads();
    if (t < 16) {
        int s = ws[t];
        #pragma unroll
        for (int o = 1; o < 16; o <<= 1) {
            int y = __shfl_up(s, o, 16);
            if (t >= o) s += y;
        }
        ws[t] = s;
    }
    __syncthreads();
    int wid = t >> 6;
    int pre = wid ? ws[wid - 1] : 0;
    if (i < n) excl[i] = pre + x - v;
    if (t == 1023) bsums[blockIdx.x] = ws[15];
}

__global__ void scan2(const int* __restrict__ bsums, int* __restrict__ boff, int nb,
                      int* __restrict__ total_out) {
    int t = threadIdx.x;  // 64 threads, nb <= 64
    int v = (t < nb) ? bsums[t] : 0;
    int x = v;
    #pragma unroll
    for (int o = 1; o < 64; o <<= 1) {
        int y = __shfl_up(x, o, 64);
        if (t >= o) x += y;
    }
    if (t < nb) boff[t] = x - v;
    if (t == 63) total_out[0] = x;
}

__global__ void scan3(int* __restrict__ off, const int* __restrict__ boff, int n) {
    int i = blockIdx.x * 1024 + threadIdx.x;
    if (i < n) off[i] += boff[blockIdx.x];
}

// ---------------- CSR fill ----------------
__global__ void fill_kernel(const int* __restrict__ src, const int* __restrict__ dst,
                            const int* __restrict__ off, int* __restrict__ cursor,
                            int* __restrict__ eidx, int E) {
    int e = blockIdx.x * blockDim.x + threadIdx.x;
    if (e < E) {
        int d = dst[e];
        int pos = off[d] + atomicAdd(&cursor[d], 1);
        eidx[pos] = src[e];
    }
}

// ---------------- dense matmul: Y = (X * norm_out_row) @ W   [n,128]x[128,128] ----------------
__global__ __launch_bounds__(256) void mm128(const float* __restrict__ X, const float* __restrict__ W,
                                             const float* __restrict__ nrm, float* __restrict__ Y, int n) {
    __shared__ float Wl[32][128];
    __shared__ float Xl[32][36];  // [k][row], pad to 36 for banks + keep float4 alignment (36*4=144=9*16)
    int t = threadIdx.x;
    int tx = t & 31;   // col group: cols 4*tx..4*tx+3
    int ty = t >> 5;   // row group: rows 4*ty..4*ty+3
    int r0 = blockIdx.x * 32;

    float acc[4][4];
    #pragma unroll
    for (int i = 0; i < 4; i++)
        #pragma unroll
        for (int j = 0; j < 4; j++) acc[i][j] = 0.f;

    for (int kt = 0; kt < HID; kt += 32) {
        // stage W tile 32x128
        #pragma unroll
        for (int i = 0; i < 4; i++) {
            int lin = i * 1024 + t * 4;
            int k = lin >> 7, c = lin & 127;
            *(float4*)&Wl[k][c] = *(const float4*)&W[(kt + k) * HID + c];
        }
        // stage X tile transposed [k][row]
        {
            int row = t >> 3;
            int k4 = (t & 7) * 4;
            float4 xv = make_float4(0.f, 0.f, 0.f, 0.f);
            int r = r0 + row;
            if (r < n) xv = *(const float4*)&X[(size_t)r * HID + kt + k4];
            Xl[k4 + 0][row] = xv.x;
            Xl[k4 + 1][row] = xv.y;
            Xl[k4 + 2][row] = xv.z;
            Xl[k4 + 3][row] = xv.w;
        }
        __syncthreads();
        #pragma unroll
        for (int k = 0; k < 32; k++) {
            float4 xv = *(float4*)&Xl[k][ty * 4];
            float4 wv = *(float4*)&Wl[k][tx * 4];
            acc[0][0] += xv.x * wv.x; acc[0][1] += xv.x * wv.y; acc[0][2] += xv.x * wv.z; acc[0][3] += xv.x * wv.w;
            acc[1][0] += xv.y * wv.x; acc[1][1] += xv.y * wv.y; acc[1][2] += xv.y * wv.z; acc[1][3] += xv.y * wv.w;
            acc[2][0] += xv.z * wv.x; acc[2][1] += xv.z * wv.y; acc[2][2] += xv.z * wv.z; acc[2][3] += xv.z * wv.w;
            acc[3][0] += xv.w * wv.x; acc[3][1] += xv.w * wv.y; acc[3][2] += xv.w * wv.z; acc[3][3] += xv.w * wv.w;
        }
        __syncthreads();
    }
    #pragma unroll
    for (int i = 0; i < 4; i++) {
        int r = r0 + ty * 4 + i;
        if (r < n) {
            float s = nrm[r];
            float4 o;
            o.x = acc[i][0] * s; o.y = acc[i][1] * s; o.z = acc[i][2] * s; o.w = acc[i][3] * s;
            *(float4*)&Y[(size_t)r * HID + tx * 4] = o;
        }
    }
}

// ---------------- fused aggregate + norm_in + bias + LayerNorm + LeakyReLU ----------------
__global__ __launch_bounds__(256) void agg_post(const float* __restrict__ Y, const int* __restrict__ off,
                                                const int* __restrict__ eidx, const float* __restrict__ nin,
                                                const float* __restrict__ b, const float* __restrict__ g,
                                                const float* __restrict__ be, float* __restrict__ Xo, int n) {
    int w = threadIdx.x >> 6, lane = threadIdx.x & 63;
    int r = blockIdx.x * 4 + w;
    if (r >= n) return;
    int s = off[r], e = off[r + 1];
    float a0 = 0.f, a1 = 0.f;
    for (int j = s; j < e; ++j) {
        int sc = eidx[j];
        float2 v = *(const float2*)&Y[(size_t)sc * HID + lane * 2];
        a0 += v.x;
        a1 += v.y;
    }
    float ni = nin[r];
    float v0 = a0 * ni + b[lane * 2];
    float v1 = a1 * ni + b[lane * 2 + 1];
    float sum = v0 + v1;
    #pragma unroll
    for (int o = 32; o >= 1; o >>= 1) sum += __shfl_xor(sum, o, 64);
    float mu = sum * (1.f / 128.f);
    float d0 = v0 - mu, d1 = v1 - mu;
    float vs = d0 * d0 + d1 * d1;
    #pragma unroll
    for (int o = 32; o >= 1; o >>= 1) vs += __shfl_xor(vs, o, 64);
    float rs = rsqrtf(vs * (1.f / 128.f) + 1e-5f);
    float y0 = d0 * rs * g[lane * 2] + be[lane * 2];
    float y1 = d1 * rs * g[lane * 2 + 1] + be[lane * 2 + 1];
    *(float2*)&Xo[(size_t)r * HID + lane * 2] = make_float2(lrelu(y0), lrelu(y1));
}

// ---------------- final projection: Z = (X * norm_out) @ W3   [n,128]x[128,2] ----------------
__global__ __launch_bounds__(256) void mm2(const float* __restrict__ X, const float* __restrict__ W3,
                                           const float* __restrict__ nout, float* __restrict__ Z, int n) {
    int w = threadIdx.x >> 6, lane = threadIdx.x & 63;
    int r = blockIdx.x * 4 + w;
    if (r >= n) return;
    float2 x = *(const float2*)&X[(size_t)r * HID + lane * 2];
    // W3 row-major [128][2]
    float a0 = x.x * W3[4 * lane + 0] + x.y * W3[4 * lane + 2];
    float a1 = x.x * W3[4 * lane + 1] + x.y * W3[4 * lane + 3];
    #pragma unroll
    for (int o = 32; o >= 1; o >>= 1) {
        a0 += __shfl_xor(a0, o, 64);
        a1 += __shfl_xor(a1, o, 64);
    }
    if (lane == 0) {
        float s = nout[r];
        *(float2*)&Z[r * 2] = make_float2(a0 * s, a1 * s);
    }
}

// ---------------- final aggregation (2 dims) ----------------
__global__ void agg3(const float* __restrict__ Z, const int* __restrict__ off,
                     const int* __restrict__ eidx, const float* __restrict__ nin,
                     const float* __restrict__ b3, float* __restrict__ out, int n) {
    int r = blockIdx.x * blockDim.x + threadIdx.x;
    if (r < n) {
        int s = off[r], e = off[r + 1];
        float a0 = 0.f, a1 = 0.f;
        for (int j = s; j < e; ++j) {
            float2 v = *(const float2*)&Z[eidx[j] * 2];
            a0 += v.x;
            a1 += v.y;
        }
        float ni = nin[r];
        out[r * 2 + 0] = a0 * ni + b3[0];
        out[r * 2 + 1] = a1 * ni + b3[1];
    }
}

extern "C" void kernel_launch(void* const* d_in, const int* in_sizes, int n_in,
                              void* d_out, int out_size, void* d_ws, size_t ws_size,
                              hipStream_t stream) {
    const float* feat = (const float*)d_in[0];
    const int* src = (const int*)d_in[1];
    const int* dst = (const int*)d_in[2];
    const float* W1 = (const float*)d_in[3];
    const float* b1 = (const float*)d_in[4];
    const float* W2 = (const float*)d_in[5];
    const float* b2 = (const float*)d_in[6];
    const float* W3 = (const float*)d_in[7];
    const float* b3 = (const float*)d_in[8];
    const float* g1 = (const float*)d_in[9];
    const float* be1 = (const float*)d_in[10];
    const float* g2 = (const float*)d_in[11];
    const float* be2 = (const float*)d_in[12];
    float* out = (float*)d_out;

    char* p = (char*)d_ws;
    auto carve = [&](size_t bytes) -> char* {
        char* q = p;
        p += (bytes + 255) & ~(size_t)255;
        return q;
    };
    float* norm_out = (float*)carve(NN * 4);
    float* norm_in  = (float*)carve(NN * 4);
    int* deg_out = (int*)carve(NN * 4);
    int* deg_in  = (int*)carve(NN * 4);
    int* cursor  = (int*)carve(NN * 4);
    int* off     = (int*)carve((NN + 1) * 4);
    int* bsums   = (int*)carve(64 * 4);
    int* boff    = (int*)carve(64 * 4);
    int* eidx    = (int*)carve((size_t)NE * 4);
    float* Y = (float*)carve((size_t)NN * HID * 4);
    float* X = (float*)carve((size_t)NN * HID * 4);
    float* Z = (float*)carve((size_t)NN * 2 * 4);

    hipMemsetAsync(deg_out, 0, NN * 4, stream);
    hipMemsetAsync(deg_in, 0, NN * 4, stream);
    hipMemsetAsync(cursor, 0, NN * 4, stream);

    deg_kernel<<<(NE + 255) / 256, 256, 0, stream>>>(src, dst, deg_out, deg_in, NE);
    norm_kernel<<<(NN + 255) / 256, 256, 0, stream>>>(deg_out, deg_in, norm_out, norm_in, NN);

    int nb = (NN + 1023) / 1024;  // 49
    scan1<<<nb, 1024, 0, stream>>>(deg_in, off, bsums, NN);
    scan2<<<1, 64, 0, stream>>>(bsums, boff, nb, off + NN);
    scan3<<<nb, 1024, 0, stream>>>(off, boff, NN);
    fill_kernel<<<(NE + 255) / 256, 256, 0, stream>>>(src, dst, off, cursor, eidx, NE);

    // layer 1
    mm128<<<(NN + 31) / 32, 256, 0, stream>>>(feat, W1, norm_out, Y, NN);
    agg_post<<<(NN + 3) / 4, 256, 0, stream>>>(Y, off, eidx, norm_in, b1, g1, be1, X, NN);
    // layer 2
    mm128<<<(NN + 31) / 32, 256, 0, stream>>>(X, W2, norm_out, Y, NN);
    agg_post<<<(NN + 3) / 4, 256, 0, stream>>>(Y, off, eidx, norm_in, b2, g2, be2, X, NN);
    // layer 3 (project to 2 dims first, then aggregate 2 floats/edge)
    mm2<<<(NN + 3) / 4, 256, 0, stream>>>(X, W3, norm_out, Z, NN);
    agg3<<<(NN + 255) / 256, 256, 0, stream>>>(Z, off, eidx, norm_in, b3, out, NN);
}

// Round 2
// 373.719 us; speedup vs baseline: 1.0348x; 1.0348x over previous
//
#include <hip/hip_runtime.h>
#include <hip/hip_fp16.h>

#define NN 50000
#define NE 800000
#define HID 128

static __device__ __forceinline__ float lrelu(float x) { return x > 0.f ? x : 0.01f * x; }

// ---------------- degree / norm ----------------
__global__ void deg_kernel(const int* __restrict__ src, const int* __restrict__ dst,
                           int* __restrict__ deg_out, int* __restrict__ deg_in, int E) {
    int e = blockIdx.x * blockDim.x + threadIdx.x;
    if (e < E) {
        atomicAdd(&deg_out[src[e]], 1);
        atomicAdd(&deg_in[dst[e]], 1);
    }
}

__global__ void norm_kernel(const int* __restrict__ deg_out, const int* __restrict__ deg_in,
                            float* __restrict__ norm_out, float* __restrict__ norm_in, int n) {
    int i = blockIdx.x * blockDim.x + threadIdx.x;
    if (i < n) {
        norm_out[i] = rsqrtf((float)max(deg_out[i], 1));
        norm_in[i]  = rsqrtf((float)max(deg_in[i], 1));
    }
}

// ---------------- prefix scan (3 kernels) ----------------
__global__ void scan1(const int* __restrict__ deg, int* __restrict__ excl,
                      int* __restrict__ bsums, int n) {
    __shared__ int ws[16];
    int t = threadIdx.x;
    int i = blockIdx.x * 1024 + t;
    int v = (i < n) ? deg[i] : 0;
    int x = v;
    #pragma unroll
    for (int o = 1; o < 64; o <<= 1) {
        int y = __shfl_up(x, o, 64);
        if ((t & 63) >= o) x += y;
    }
    if ((t & 63) == 63) ws[t >> 6] = x;
    __syncthreads();
    if (t < 16) {
        int s = ws[t];
        #pragma unroll
        for (int o = 1; o < 16; o <<= 1) {
            int y = __shfl_up(s, o, 16);
            if (t >= o) s += y;
        }
        ws[t] = s;
    }
    __syncthreads();
    int wid = t >> 6;
    int pre = wid ? ws[wid - 1] : 0;
    if (i < n) excl[i] = pre + x - v;
    if (t == 1023) bsums[blockIdx.x] = ws[15];
}

__global__ void scan2(const int* __restrict__ bsums, int* __restrict__ boff, int nb,
                      int* __restrict__ total_out) {
    int t = threadIdx.x;  // 64 threads, nb <= 64
    int v = (t < nb) ? bsums[t] : 0;
    int x = v;
    #pragma unroll
    for (int o = 1; o < 64; o <<= 1) {
        int y = __shfl_up(x, o, 64);
        if (t >= o) x += y;
    }
    if (t < nb) boff[t] = x - v;
    if (t == 63) total_out[0] = x;
}

__global__ void scan3(int* __restrict__ off, const int* __restrict__ boff, int n) {
    int i = blockIdx.x * 1024 + threadIdx.x;
    if (i < n) off[i] += boff[blockIdx.x];
}

// ---------------- CSR fill ----------------
__global__ void fill_kernel(const int* __restrict__ src, const int* __restrict__ dst,
                            const int* __restrict__ off, int* __restrict__ cursor,
                            int* __restrict__ eidx, int E) {
    int e = blockIdx.x * blockDim.x + threadIdx.x;
    if (e < E) {
        int d = dst[e];
        int pos = off[d] + atomicAdd(&cursor[d], 1);
        eidx[pos] = src[e];
    }
}

// ---------------- dense matmul: Yh = fp16((X * norm_out_row) @ W)   [n,128]x[128,128] ----------------
__global__ __launch_bounds__(256) void mm128(const float* __restrict__ X, const float* __restrict__ W,
                                             const float* __restrict__ nrm, __half* __restrict__ Yh, int n) {
    __shared__ float Wl[32][128];
    __shared__ float Xl[32][36];  // [k][row], pad to 36 (36*4=144=9*16 keeps float4 alignment)
    int t = threadIdx.x;
    int tx = t & 31;   // col group: cols 4*tx..4*tx+3
    int ty = t >> 5;   // row group: rows 4*ty..4*ty+3
    int r0 = blockIdx.x * 32;

    float acc[4][4];
    #pragma unroll
    for (int i = 0; i < 4; i++)
        #pragma unroll
        for (int j = 0; j < 4; j++) acc[i][j] = 0.f;

    for (int kt = 0; kt < HID; kt += 32) {
        #pragma unroll
        for (int i = 0; i < 4; i++) {
            int lin = i * 1024 + t * 4;
            int k = lin >> 7, c = lin & 127;
            *(float4*)&Wl[k][c] = *(const float4*)&W[(kt + k) * HID + c];
        }
        {
            int row = t >> 3;
            int k4 = (t & 7) * 4;
            float4 xv = make_float4(0.f, 0.f, 0.f, 0.f);
            int r = r0 + row;
            if (r < n) xv = *(const float4*)&X[(size_t)r * HID + kt + k4];
            Xl[k4 + 0][row] = xv.x;
            Xl[k4 + 1][row] = xv.y;
            Xl[k4 + 2][row] = xv.z;
            Xl[k4 + 3][row] = xv.w;
        }
        __syncthreads();
        #pragma unroll
        for (int k = 0; k < 32; k++) {
            float4 xv = *(float4*)&Xl[k][ty * 4];
            float4 wv = *(float4*)&Wl[k][tx * 4];
            acc[0][0] += xv.x * wv.x; acc[0][1] += xv.x * wv.y; acc[0][2] += xv.x * wv.z; acc[0][3] += xv.x * wv.w;
            acc[1][0] += xv.y * wv.x; acc[1][1] += xv.y * wv.y; acc[1][2] += xv.y * wv.z; acc[1][3] += xv.y * wv.w;
            acc[2][0] += xv.z * wv.x; acc[2][1] += xv.z * wv.y; acc[2][2] += xv.z * wv.z; acc[2][3] += xv.z * wv.w;
            acc[3][0] += xv.w * wv.x; acc[3][1] += xv.w * wv.y; acc[3][2] += xv.w * wv.z; acc[3][3] += xv.w * wv.w;
        }
        __syncthreads();
    }
    #pragma unroll
    for (int i = 0; i < 4; i++) {
        int r = r0 + ty * 4 + i;
        if (r < n) {
            float s = nrm[r];
            union { __half2 h[2]; float2 f; } u;
            u.h[0] = __floats2half2_rn(acc[i][0] * s, acc[i][1] * s);
            u.h[1] = __floats2half2_rn(acc[i][2] * s, acc[i][3] * s);
            *(float2*)&Yh[(size_t)r * HID + tx * 4] = u.f;
        }
    }
}

// ---------------- fused aggregate(fp16 gather) + norm_in + bias + LayerNorm + LeakyReLU ----------------
__global__ __launch_bounds__(256) void agg_post(const __half2* __restrict__ Yh2, const int* __restrict__ off,
                                                const int* __restrict__ eidx, const float* __restrict__ nin,
                                                const float* __restrict__ b, const float* __restrict__ g,
                                                const float* __restrict__ be, float* __restrict__ Xo, int n) {
    int w = threadIdx.x >> 6, lane = threadIdx.x & 63;
    int r = blockIdx.x * 4 + w;
    if (r >= n) return;
    int s = off[r], e = off[r + 1];
    float a0 = 0.f, a1 = 0.f;
    for (int j = s; j < e; ++j) {
        int sc = eidx[j];
        __half2 v = Yh2[(size_t)sc * 64 + lane];
        float2 f = __half22float2(v);
        a0 += f.x;
        a1 += f.y;
    }
    float ni = nin[r];
    float v0 = a0 * ni + b[lane * 2];
    float v1 = a1 * ni + b[lane * 2 + 1];
    float sum = v0 + v1;
    #pragma unroll
    for (int o = 32; o >= 1; o >>= 1) sum += __shfl_xor(sum, o, 64);
    float mu = sum * (1.f / 128.f);
    float d0 = v0 - mu, d1 = v1 - mu;
    float vs = d0 * d0 + d1 * d1;
    #pragma unroll
    for (int o = 32; o >= 1; o >>= 1) vs += __shfl_xor(vs, o, 64);
    float rs = rsqrtf(vs * (1.f / 128.f) + 1e-5f);
    float y0 = d0 * rs * g[lane * 2] + be[lane * 2];
    float y1 = d1 * rs * g[lane * 2 + 1] + be[lane * 2 + 1];
    *(float2*)&Xo[(size_t)r * HID + lane * 2] = make_float2(lrelu(y0), lrelu(y1));
}

// ---------------- final projection: Z = (X * norm_out) @ W3   [n,128]x[128,2] ----------------
__global__ __launch_bounds__(256) void mm2(const float* __restrict__ X, const float* __restrict__ W3,
                                           const float* __restrict__ nout, float* __restrict__ Z, int n) {
    int w = threadIdx.x >> 6, lane = threadIdx.x & 63;
    int r = blockIdx.x * 4 + w;
    if (r >= n) return;
    float2 x = *(const float2*)&X[(size_t)r * HID + lane * 2];
    float a0 = x.x * W3[4 * lane + 0] + x.y * W3[4 * lane + 2];
    float a1 = x.x * W3[4 * lane + 1] + x.y * W3[4 * lane + 3];
    #pragma unroll
    for (int o = 32; o >= 1; o >>= 1) {
        a0 += __shfl_xor(a0, o, 64);
        a1 += __shfl_xor(a1, o, 64);
    }
    if (lane == 0) {
        float s = nout[r];
        *(float2*)&Z[r * 2] = make_float2(a0 * s, a1 * s);
    }
}

// ---------------- final aggregation (2 dims) ----------------
__global__ void agg3(const float* __restrict__ Z, const int* __restrict__ off,
                     const int* __restrict__ eidx, const float* __restrict__ nin,
                     const float* __restrict__ b3, float* __restrict__ out, int n) {
    int r = blockIdx.x * blockDim.x + threadIdx.x;
    if (r < n) {
        int s = off[r], e = off[r + 1];
        float a0 = 0.f, a1 = 0.f;
        for (int j = s; j < e; ++j) {
            float2 v = *(const float2*)&Z[eidx[j] * 2];
            a0 += v.x;
            a1 += v.y;
        }
        float ni = nin[r];
        out[r * 2 + 0] = a0 * ni + b3[0];
        out[r * 2 + 1] = a1 * ni + b3[1];
    }
}

extern "C" void kernel_launch(void* const* d_in, const int* in_sizes, int n_in,
                              void* d_out, int out_size, void* d_ws, size_t ws_size,
                              hipStream_t stream) {
    const float* feat = (const float*)d_in[0];
    const int* src = (const int*)d_in[1];
    const int* dst = (const int*)d_in[2];
    const float* W1 = (const float*)d_in[3];
    const float* b1 = (const float*)d_in[4];
    const float* W2 = (const float*)d_in[5];
    const float* b2 = (const float*)d_in[6];
    const float* W3 = (const float*)d_in[7];
    const float* b3 = (const float*)d_in[8];
    const float* g1 = (const float*)d_in[9];
    const float* be1 = (const float*)d_in[10];
    const float* g2 = (const float*)d_in[11];
    const float* be2 = (const float*)d_in[12];
    float* out = (float*)d_out;

    char* p = (char*)d_ws;
    auto carve = [&](size_t bytes) -> char* {
        char* q = p;
        p += (bytes + 255) & ~(size_t)255;
        return q;
    };
    float* norm_out = (float*)carve(NN * 4);
    float* norm_in  = (float*)carve(NN * 4);
    int* deg_out = (int*)carve(NN * 4);
    int* deg_in  = (int*)carve(NN * 4);
    int* cursor  = (int*)carve(NN * 4);
    int* off     = (int*)carve((NN + 1) * 4);
    int* bsums   = (int*)carve(64 * 4);
    int* boff    = (int*)carve(64 * 4);
    int* eidx    = (int*)carve((size_t)NE * 4);
    __half* Yh = (__half*)carve((size_t)NN * HID * 2);
    float* X = (float*)carve((size_t)NN * HID * 4);
    float* Z = (float*)carve((size_t)NN * 2 * 4);

    hipMemsetAsync(deg_out, 0, NN * 4, stream);
    hipMemsetAsync(deg_in, 0, NN * 4, stream);
    hipMemsetAsync(cursor, 0, NN * 4, stream);

    deg_kernel<<<(NE + 255) / 256, 256, 0, stream>>>(src, dst, deg_out, deg_in, NE);
    norm_kernel<<<(NN + 255) / 256, 256, 0, stream>>>(deg_out, deg_in, norm_out, norm_in, NN);

    int nb = (NN + 1023) / 1024;  // 49
    scan1<<<nb, 1024, 0, stream>>>(deg_in, off, bsums, NN);
    scan2<<<1, 64, 0, stream>>>(bsums, boff, nb, off + NN);
    scan3<<<nb, 1024, 0, stream>>>(off, boff, NN);
    fill_kernel<<<(NE + 255) / 256, 256, 0, stream>>>(src, dst, off, cursor, eidx, NE);

    // layer 1
    mm128<<<(NN + 31) / 32, 256, 0, stream>>>(feat, W1, norm_out, Yh, NN);
    agg_post<<<(NN + 3) / 4, 256, 0, stream>>>((const __half2*)Yh, off, eidx, norm_in, b1, g1, be1, X, NN);
    // layer 2
    mm128<<<(NN + 31) / 32, 256, 0, stream>>>(X, W2, norm_out, Yh, NN);
    agg_post<<<(NN + 3) / 4, 256, 0, stream>>>((const __half2*)Yh, off, eidx, norm_in, b2, g2, be2, X, NN);
    // layer 3 (project to 2 dims first, then aggregate 2 floats/edge)
    mm2<<<(NN + 3) / 4, 256, 0, stream>>>(X, W3, norm_out, Z, NN);
    agg3<<<(NN + 255) / 256, 256, 0, stream>>>(Z, off, eidx, norm_in, b3, out, NN);
}

// Round 3
// 292.448 us; speedup vs baseline: 1.3223x; 1.2779x over previous
//
#include <hip/hip_runtime.h>
#include <hip/hip_fp16.h>

#define NN 50000
#define NE 800000
#define HID 128

static __device__ __forceinline__ float lrelu(float x) { return x > 0.f ? x : 0.01f * x; }

// ---------------- degree / norm ----------------
__global__ void deg_kernel(const int* __restrict__ src, const int* __restrict__ dst,
                           int* __restrict__ deg_out, int* __restrict__ deg_in, int E) {
    int e = blockIdx.x * blockDim.x + threadIdx.x;
    if (e < E) {
        atomicAdd(&deg_out[src[e]], 1);
        atomicAdd(&deg_in[dst[e]], 1);
    }
}

__global__ void norm_kernel(const int* __restrict__ deg_out, const int* __restrict__ deg_in,
                            float* __restrict__ norm_out, float* __restrict__ norm_in, int n) {
    int i = blockIdx.x * blockDim.x + threadIdx.x;
    if (i < n) {
        norm_out[i] = rsqrtf((float)max(deg_out[i], 1));
        norm_in[i]  = rsqrtf((float)max(deg_in[i], 1));
    }
}

// ---------------- prefix scan (3 kernels) ----------------
__global__ void scan1(const int* __restrict__ deg, int* __restrict__ excl,
                      int* __restrict__ bsums, int n) {
    __shared__ int ws[16];
    int t = threadIdx.x;
    int i = blockIdx.x * 1024 + t;
    int v = (i < n) ? deg[i] : 0;
    int x = v;
    #pragma unroll
    for (int o = 1; o < 64; o <<= 1) {
        int y = __shfl_up(x, o, 64);
        if ((t & 63) >= o) x += y;
    }
    if ((t & 63) == 63) ws[t >> 6] = x;
    __syncthreads();
    if (t < 16) {
        int s = ws[t];
        #pragma unroll
        for (int o = 1; o < 16; o <<= 1) {
            int y = __shfl_up(s, o, 16);
            if (t >= o) s += y;
        }
        ws[t] = s;
    }
    __syncthreads();
    int wid = t >> 6;
    int pre = wid ? ws[wid - 1] : 0;
    if (i < n) excl[i] = pre + x - v;
    if (t == 1023) bsums[blockIdx.x] = ws[15];
}

__global__ void scan2(const int* __restrict__ bsums, int* __restrict__ boff, int nb,
                      int* __restrict__ total_out) {
    int t = threadIdx.x;  // 64 threads, nb <= 64
    int v = (t < nb) ? bsums[t] : 0;
    int x = v;
    #pragma unroll
    for (int o = 1; o < 64; o <<= 1) {
        int y = __shfl_up(x, o, 64);
        if (t >= o) x += y;
    }
    if (t < nb) boff[t] = x - v;
    if (t == 63) total_out[0] = x;
}

__global__ void scan3(int* __restrict__ off, const int* __restrict__ boff, int n) {
    int i = blockIdx.x * 1024 + threadIdx.x;
    if (i < n) off[i] += boff[blockIdx.x];
}

// ---------------- CSR fill ----------------
__global__ void fill_kernel(const int* __restrict__ src, const int* __restrict__ dst,
                            const int* __restrict__ off, int* __restrict__ cursor,
                            int* __restrict__ eidx, int E) {
    int e = blockIdx.x * blockDim.x + threadIdx.x;
    if (e < E) {
        int d = dst[e];
        int pos = off[d] + atomicAdd(&cursor[d], 1);
        eidx[pos] = src[e];
    }
}

// ---------------- dense matmul: Yh = fp16((X * norm_out_row) @ W)   [n,128]x[128,128] ----------------
__global__ __launch_bounds__(256) void mm128(const float* __restrict__ X, const float* __restrict__ W,
                                             const float* __restrict__ nrm, __half* __restrict__ Yh, int n) {
    __shared__ float Wl[32][128];
    __shared__ float Xl[32][36];
    int t = threadIdx.x;
    int tx = t & 31;
    int ty = t >> 5;
    int r0 = blockIdx.x * 32;

    float acc[4][4];
    #pragma unroll
    for (int i = 0; i < 4; i++)
        #pragma unroll
        for (int j = 0; j < 4; j++) acc[i][j] = 0.f;

    for (int kt = 0; kt < HID; kt += 32) {
        #pragma unroll
        for (int i = 0; i < 4; i++) {
            int lin = i * 1024 + t * 4;
            int k = lin >> 7, c = lin & 127;
            *(float4*)&Wl[k][c] = *(const float4*)&W[(kt + k) * HID + c];
        }
        {
            int row = t >> 3;
            int k4 = (t & 7) * 4;
            float4 xv = make_float4(0.f, 0.f, 0.f, 0.f);
            int r = r0 + row;
            if (r < n) xv = *(const float4*)&X[(size_t)r * HID + kt + k4];
            Xl[k4 + 0][row] = xv.x;
            Xl[k4 + 1][row] = xv.y;
            Xl[k4 + 2][row] = xv.z;
            Xl[k4 + 3][row] = xv.w;
        }
        __syncthreads();
        #pragma unroll
        for (int k = 0; k < 32; k++) {
            float4 xv = *(float4*)&Xl[k][ty * 4];
            float4 wv = *(float4*)&Wl[k][tx * 4];
            acc[0][0] += xv.x * wv.x; acc[0][1] += xv.x * wv.y; acc[0][2] += xv.x * wv.z; acc[0][3] += xv.x * wv.w;
            acc[1][0] += xv.y * wv.x; acc[1][1] += xv.y * wv.y; acc[1][2] += xv.y * wv.z; acc[1][3] += xv.y * wv.w;
            acc[2][0] += xv.z * wv.x; acc[2][1] += xv.z * wv.y; acc[2][2] += xv.z * wv.z; acc[2][3] += xv.z * wv.w;
            acc[3][0] += xv.w * wv.x; acc[3][1] += xv.w * wv.y; acc[3][2] += xv.w * wv.z; acc[3][3] += xv.w * wv.w;
        }
        __syncthreads();
    }
    #pragma unroll
    for (int i = 0; i < 4; i++) {
        int r = r0 + ty * 4 + i;
        if (r < n) {
            float s = nrm[r];
            union { __half2 h[2]; float2 f; } u;
            u.h[0] = __floats2half2_rn(acc[i][0] * s, acc[i][1] * s);
            u.h[1] = __floats2half2_rn(acc[i][2] * s, acc[i][3] * s);
            *(float2*)&Yh[(size_t)r * HID + tx * 4] = u.f;
        }
    }
}

// ---------------- fused aggregate(fp16 gather, 4 edges x 16 lanes x 16B) + LN + LeakyReLU ----------------
__global__ __launch_bounds__(256) void agg_post(const __half* __restrict__ Yh, const int* __restrict__ off,
                                                const int* __restrict__ eidx, const float* __restrict__ nin,
                                                const float* __restrict__ bias, const float* __restrict__ gam,
                                                const float* __restrict__ bet, float* __restrict__ Xo, int n) {
    int w = threadIdx.x >> 6, lane = threadIdx.x & 63;
    int r = blockIdx.x * 4 + w;
    if (r >= n) return;
    int grp = lane >> 4;       // which edge within a 4-edge batch
    int s16 = lane & 15;       // which 8-feature chunk
    int f0 = s16 * 8;
    int s = off[r], e = off[r + 1];

    float af[8];
    #pragma unroll
    for (int i = 0; i < 8; i++) af[i] = 0.f;

    union U { float4 f; __half2 h[4]; };
    for (int j = s; j < e; j += 8) {
        int ia = j + grp, ib = j + 4 + grp;
        bool va = ia < e, vb = ib < e;
        U u1, u2;
        if (va) { int sc = eidx[ia]; u1.f = *(const float4*)&Yh[(size_t)sc * HID + f0]; }
        if (vb) { int sc = eidx[ib]; u2.f = *(const float4*)&Yh[(size_t)sc * HID + f0]; }
        if (va) {
            #pragma unroll
            for (int k = 0; k < 4; k++) {
                float2 f = __half22float2(u1.h[k]);
                af[2 * k] += f.x; af[2 * k + 1] += f.y;
            }
        }
        if (vb) {
            #pragma unroll
            for (int k = 0; k < 4; k++) {
                float2 f = __half22float2(u2.h[k]);
                af[2 * k] += f.x; af[2 * k + 1] += f.y;
            }
        }
    }
    // combine the 4 edge-groups (lanes differing in bits 4,5)
    #pragma unroll
    for (int i = 0; i < 8; i++) {
        af[i] += __shfl_xor(af[i], 16, 64);
        af[i] += __shfl_xor(af[i], 32, 64);
    }

    float ni = nin[r];
    float4 b0 = *(const float4*)&bias[f0];
    float4 b1 = *(const float4*)&bias[f0 + 4];
    float v[8];
    v[0] = af[0] * ni + b0.x; v[1] = af[1] * ni + b0.y;
    v[2] = af[2] * ni + b0.z; v[3] = af[3] * ni + b0.w;
    v[4] = af[4] * ni + b1.x; v[5] = af[5] * ni + b1.y;
    v[6] = af[6] * ni + b1.z; v[7] = af[7] * ni + b1.w;

    float sum = 0.f;
    #pragma unroll
    for (int i = 0; i < 8; i++) sum += v[i];
    #pragma unroll
    for (int o = 8; o >= 1; o >>= 1) sum += __shfl_xor(sum, o, 64);
    float mu = sum * (1.f / 128.f);

    float d[8], vs = 0.f;
    #pragma unroll
    for (int i = 0; i < 8; i++) { d[i] = v[i] - mu; vs += d[i] * d[i]; }
    #pragma unroll
    for (int o = 8; o >= 1; o >>= 1) vs += __shfl_xor(vs, o, 64);
    float rs = rsqrtf(vs * (1.f / 128.f) + 1e-5f);

    float4 g0 = *(const float4*)&gam[f0];
    float4 g1 = *(const float4*)&gam[f0 + 4];
    float4 e0 = *(const float4*)&bet[f0];
    float4 e1 = *(const float4*)&bet[f0 + 4];
    if (grp == 0) {
        float4 o0, o1;
        o0.x = lrelu(d[0] * rs * g0.x + e0.x);
        o0.y = lrelu(d[1] * rs * g0.y + e0.y);
        o0.z = lrelu(d[2] * rs * g0.z + e0.z);
        o0.w = lrelu(d[3] * rs * g0.w + e0.w);
        o1.x = lrelu(d[4] * rs * g1.x + e1.x);
        o1.y = lrelu(d[5] * rs * g1.y + e1.y);
        o1.z = lrelu(d[6] * rs * g1.z + e1.z);
        o1.w = lrelu(d[7] * rs * g1.w + e1.w);
        *(float4*)&Xo[(size_t)r * HID + f0] = o0;
        *(float4*)&Xo[(size_t)r * HID + f0 + 4] = o1;
    }
}

// ---------------- final projection: Z = (X * norm_out) @ W3   [n,128]x[128,2] ----------------
__global__ __launch_bounds__(256) void mm2(const float* __restrict__ X, const float* __restrict__ W3,
                                           const float* __restrict__ nout, float* __restrict__ Z, int n) {
    int w = threadIdx.x >> 6, lane = threadIdx.x & 63;
    int r = blockIdx.x * 4 + w;
    if (r >= n) return;
    float2 x = *(const float2*)&X[(size_t)r * HID + lane * 2];
    float a0 = x.x * W3[4 * lane + 0] + x.y * W3[4 * lane + 2];
    float a1 = x.x * W3[4 * lane + 1] + x.y * W3[4 * lane + 3];
    #pragma unroll
    for (int o = 32; o >= 1; o >>= 1) {
        a0 += __shfl_xor(a0, o, 64);
        a1 += __shfl_xor(a1, o, 64);
    }
    if (lane == 0) {
        float s = nout[r];
        *(float2*)&Z[r * 2] = make_float2(a0 * s, a1 * s);
    }
}

// ---------------- final aggregation (2 dims), 4-way unrolled for MLP ----------------
__global__ void agg3(const float* __restrict__ Z, const int* __restrict__ off,
                     const int* __restrict__ eidx, const float* __restrict__ nin,
                     const float* __restrict__ b3, float* __restrict__ out, int n) {
    int r = blockIdx.x * blockDim.x + threadIdx.x;
    if (r < n) {
        int s = off[r], e = off[r + 1];
        float p0 = 0.f, p1 = 0.f, q0 = 0.f, q1 = 0.f;
        float u0 = 0.f, u1 = 0.f, w0 = 0.f, w1 = 0.f;
        int j = s;
        for (; j + 3 < e; j += 4) {
            float2 v0 = *(const float2*)&Z[eidx[j] * 2];
            float2 v1 = *(const float2*)&Z[eidx[j + 1] * 2];
            float2 v2 = *(const float2*)&Z[eidx[j + 2] * 2];
            float2 v3 = *(const float2*)&Z[eidx[j + 3] * 2];
            p0 += v0.x; p1 += v0.y;
            q0 += v1.x; q1 += v1.y;
            u0 += v2.x; u1 += v2.y;
            w0 += v3.x; w1 += v3.y;
        }
        for (; j < e; ++j) {
            float2 v = *(const float2*)&Z[eidx[j] * 2];
            p0 += v.x; p1 += v.y;
        }
        float a0 = (p0 + q0) + (u0 + w0);
        float a1 = (p1 + q1) + (u1 + w1);
        float ni = nin[r];
        out[r * 2 + 0] = a0 * ni + b3[0];
        out[r * 2 + 1] = a1 * ni + b3[1];
    }
}

extern "C" void kernel_launch(void* const* d_in, const int* in_sizes, int n_in,
                              void* d_out, int out_size, void* d_ws, size_t ws_size,
                              hipStream_t stream) {
    const float* feat = (const float*)d_in[0];
    const int* src = (const int*)d_in[1];
    const int* dst = (const int*)d_in[2];
    const float* W1 = (const float*)d_in[3];
    const float* b1 = (const float*)d_in[4];
    const float* W2 = (const float*)d_in[5];
    const float* b2 = (const float*)d_in[6];
    const float* W3 = (const float*)d_in[7];
    const float* b3 = (const float*)d_in[8];
    const float* g1 = (const float*)d_in[9];
    const float* be1 = (const float*)d_in[10];
    const float* g2 = (const float*)d_in[11];
    const float* be2 = (const float*)d_in[12];
    float* out = (float*)d_out;

    char* p = (char*)d_ws;
    auto carve = [&](size_t bytes) -> char* {
        char* q = p;
        p += (bytes + 255) & ~(size_t)255;
        return q;
    };
    float* norm_out = (float*)carve(NN * 4);
    float* norm_in  = (float*)carve(NN * 4);
    int* deg_out = (int*)carve(NN * 4);
    int* deg_in  = (int*)carve(NN * 4);
    int* cursor  = (int*)carve(NN * 4);
    int* off     = (int*)carve((NN + 1) * 4);
    int* bsums   = (int*)carve(64 * 4);
    int* boff    = (int*)carve(64 * 4);
    int* eidx    = (int*)carve((size_t)NE * 4);
    __half* Yh = (__half*)carve((size_t)NN * HID * 2);
    float* X = (float*)carve((size_t)NN * HID * 4);
    float* Z = (float*)carve((size_t)NN * 2 * 4);

    hipMemsetAsync(deg_out, 0, NN * 4, stream);
    hipMemsetAsync(deg_in, 0, NN * 4, stream);
    hipMemsetAsync(cursor, 0, NN * 4, stream);

    deg_kernel<<<(NE + 255) / 256, 256, 0, stream>>>(src, dst, deg_out, deg_in, NE);
    norm_kernel<<<(NN + 255) / 256, 256, 0, stream>>>(deg_out, deg_in, norm_out, norm_in, NN);

    int nb = (NN + 1023) / 1024;  // 49
    scan1<<<nb, 1024, 0, stream>>>(deg_in, off, bsums, NN);
    scan2<<<1, 64, 0, stream>>>(bsums, boff, nb, off + NN);
    scan3<<<nb, 1024, 0, stream>>>(off, boff, NN);
    fill_kernel<<<(NE + 255) / 256, 256, 0, stream>>>(src, dst, off, cursor, eidx, NE);

    // layer 1
    mm128<<<(NN + 31) / 32, 256, 0, stream>>>(feat, W1, norm_out, Yh, NN);
    agg_post<<<(NN + 3) / 4, 256, 0, stream>>>(Yh, off, eidx, norm_in, b1, g1, be1, X, NN);
    // layer 2
    mm128<<<(NN + 31) / 32, 256, 0, stream>>>(X, W2, norm_out, Yh, NN);
    agg_post<<<(NN + 3) / 4, 256, 0, stream>>>(Yh, off, eidx, norm_in, b2, g2, be2, X, NN);
    // layer 3 (project to 2 dims first, then aggregate 2 floats/edge)
    mm2<<<(NN + 3) / 4, 256, 0, stream>>>(X, W3, norm_out, Z, NN);
    agg3<<<(NN + 255) / 256, 256, 0, stream>>>(Z, off, eidx, norm_in, b3, out, NN);
}

// Round 4
// 236.160 us; speedup vs baseline: 1.6375x; 1.2383x over previous
//
#include <hip/hip_runtime.h>
#include <hip/hip_fp16.h>

#define NN 50000
#define NE 800000
#define HID 128
#define DEGB 512          // blocks dedicated to degree counting inside mega1
#define GEMMB ((NN + 31) / 32)

static __device__ __forceinline__ float lrelu(float x) { return x > 0.f ? x : 0.01f * x; }

// ---------------- norm ----------------
__global__ void norm_kernel(const int* __restrict__ deg_out, const int* __restrict__ deg_in,
                            float* __restrict__ norm_out, float* __restrict__ norm_in, int n) {
    int i = blockIdx.x * blockDim.x + threadIdx.x;
    if (i < n) {
        norm_out[i] = rsqrtf((float)max(deg_out[i], 1));
        norm_in[i]  = rsqrtf((float)max(deg_in[i], 1));
    }
}

// ---------------- prefix scan (3 kernels) ----------------
__global__ void scan1(const int* __restrict__ deg, int* __restrict__ excl,
                      int* __restrict__ bsums, int n) {
    __shared__ int ws[16];
    int t = threadIdx.x;
    int i = blockIdx.x * 1024 + t;
    int v = (i < n) ? deg[i] : 0;
    int x = v;
    #pragma unroll
    for (int o = 1; o < 64; o <<= 1) {
        int y = __shfl_up(x, o, 64);
        if ((t & 63) >= o) x += y;
    }
    if ((t & 63) == 63) ws[t >> 6] = x;
    __syncthreads();
    if (t < 16) {
        int s = ws[t];
        #pragma unroll
        for (int o = 1; o < 16; o <<= 1) {
            int y = __shfl_up(s, o, 16);
            if (t >= o) s += y;
        }
        ws[t] = s;
    }
    __syncthreads();
    int wid = t >> 6;
    int pre = wid ? ws[wid - 1] : 0;
    if (i < n) excl[i] = pre + x - v;
    if (t == 1023) bsums[blockIdx.x] = ws[15];
}

__global__ void scan2(const int* __restrict__ bsums, int* __restrict__ boff, int nb,
                      int* __restrict__ total_out) {
    int t = threadIdx.x;
    int v = (t < nb) ? bsums[t] : 0;
    int x = v;
    #pragma unroll
    for (int o = 1; o < 64; o <<= 1) {
        int y = __shfl_up(x, o, 64);
        if (t >= o) x += y;
    }
    if (t < nb) boff[t] = x - v;
    if (t == 63) total_out[0] = x;
}

__global__ void scan3(int* __restrict__ off, const int* __restrict__ boff, int n) {
    int i = blockIdx.x * 1024 + threadIdx.x;
    if (i < n) off[i] += boff[blockIdx.x];
}

// ---------------- CSR fill: atomic-free (uses rank captured during counting) ----------------
__global__ void fill_kernel(const int* __restrict__ src, const int* __restrict__ dst,
                            const int* __restrict__ off, const int* __restrict__ rank,
                            int* __restrict__ eidx, int E) {
    int e = blockIdx.x * blockDim.x + threadIdx.x;
    if (e < E) {
        eidx[off[dst[e]] + rank[e]] = src[e];
    }
}

// ---------------- mega1: degree counting (blocks 0..DEGB-1)  ||  GEMM-1 (rest) ----------------
// GEMM computes UNNORMALIZED Yh = fp16(feat @ W1); norm_out is folded into the gather later.
__global__ __launch_bounds__(256) void mega1(const float* __restrict__ X, const float* __restrict__ W,
                                             __half* __restrict__ Yh,
                                             const int* __restrict__ src, const int* __restrict__ dst,
                                             int* __restrict__ deg_out, int* __restrict__ deg_in,
                                             int* __restrict__ rank, int n) {
    __shared__ float Wl[32][128];
    __shared__ float Xl[32][36];
    if (blockIdx.x < DEGB) {
        int tid = blockIdx.x * 256 + threadIdx.x;
        for (int e = tid; e < NE; e += DEGB * 256) {
            atomicAdd(&deg_out[src[e]], 1);           // fire-and-forget
            rank[e] = atomicAdd(&deg_in[dst[e]], 1);  // returned old value = rank in dst segment
        }
        return;
    }
    int t = threadIdx.x;
    int tx = t & 31;
    int ty = t >> 5;
    int r0 = (blockIdx.x - DEGB) * 32;

    float acc[4][4];
    #pragma unroll
    for (int i = 0; i < 4; i++)
        #pragma unroll
        for (int j = 0; j < 4; j++) acc[i][j] = 0.f;

    for (int kt = 0; kt < HID; kt += 32) {
        #pragma unroll
        for (int i = 0; i < 4; i++) {
            int lin = i * 1024 + t * 4;
            int k = lin >> 7, c = lin & 127;
            *(float4*)&Wl[k][c] = *(const float4*)&W[(kt + k) * HID + c];
        }
        {
            int row = t >> 3;
            int k4 = (t & 7) * 4;
            float4 xv = make_float4(0.f, 0.f, 0.f, 0.f);
            int r = r0 + row;
            if (r < n) xv = *(const float4*)&X[(size_t)r * HID + kt + k4];
            Xl[k4 + 0][row] = xv.x;
            Xl[k4 + 1][row] = xv.y;
            Xl[k4 + 2][row] = xv.z;
            Xl[k4 + 3][row] = xv.w;
        }
        __syncthreads();
        #pragma unroll
        for (int k = 0; k < 32; k++) {
            float4 xv = *(float4*)&Xl[k][ty * 4];
            float4 wv = *(float4*)&Wl[k][tx * 4];
            acc[0][0] += xv.x * wv.x; acc[0][1] += xv.x * wv.y; acc[0][2] += xv.x * wv.z; acc[0][3] += xv.x * wv.w;
            acc[1][0] += xv.y * wv.x; acc[1][1] += xv.y * wv.y; acc[1][2] += xv.y * wv.z; acc[1][3] += xv.y * wv.w;
            acc[2][0] += xv.z * wv.x; acc[2][1] += xv.z * wv.y; acc[2][2] += xv.z * wv.z; acc[2][3] += xv.z * wv.w;
            acc[3][0] += xv.w * wv.x; acc[3][1] += xv.w * wv.y; acc[3][2] += xv.w * wv.z; acc[3][3] += xv.w * wv.w;
        }
        __syncthreads();
    }
    #pragma unroll
    for (int i = 0; i < 4; i++) {
        int r = r0 + ty * 4 + i;
        if (r < n) {
            union { __half2 h[2]; float2 f; } u;
            u.h[0] = __floats2half2_rn(acc[i][0], acc[i][1]);
            u.h[1] = __floats2half2_rn(acc[i][2], acc[i][3]);
            *(float2*)&Yh[(size_t)r * HID + tx * 4] = u.f;
        }
    }
}

// ---------------- plain unnormalized GEMM (layer 2): Yh = fp16(X @ W) ----------------
__global__ __launch_bounds__(256) void mm128(const float* __restrict__ X, const float* __restrict__ W,
                                             __half* __restrict__ Yh, int n) {
    __shared__ float Wl[32][128];
    __shared__ float Xl[32][36];
    int t = threadIdx.x;
    int tx = t & 31;
    int ty = t >> 5;
    int r0 = blockIdx.x * 32;

    float acc[4][4];
    #pragma unroll
    for (int i = 0; i < 4; i++)
        #pragma unroll
        for (int j = 0; j < 4; j++) acc[i][j] = 0.f;

    for (int kt = 0; kt < HID; kt += 32) {
        #pragma unroll
        for (int i = 0; i < 4; i++) {
            int lin = i * 1024 + t * 4;
            int k = lin >> 7, c = lin & 127;
            *(float4*)&Wl[k][c] = *(const float4*)&W[(kt + k) * HID + c];
        }
        {
            int row = t >> 3;
            int k4 = (t & 7) * 4;
            float4 xv = make_float4(0.f, 0.f, 0.f, 0.f);
            int r = r0 + row;
            if (r < n) xv = *(const float4*)&X[(size_t)r * HID + kt + k4];
            Xl[k4 + 0][row] = xv.x;
            Xl[k4 + 1][row] = xv.y;
            Xl[k4 + 2][row] = xv.z;
            Xl[k4 + 3][row] = xv.w;
        }
        __syncthreads();
        #pragma unroll
        for (int k = 0; k < 32; k++) {
            float4 xv = *(float4*)&Xl[k][ty * 4];
            float4 wv = *(float4*)&Wl[k][tx * 4];
            acc[0][0] += xv.x * wv.x; acc[0][1] += xv.x * wv.y; acc[0][2] += xv.x * wv.z; acc[0][3] += xv.x * wv.w;
            acc[1][0] += xv.y * wv.x; acc[1][1] += xv.y * wv.y; acc[1][2] += xv.y * wv.z; acc[1][3] += xv.y * wv.w;
            acc[2][0] += xv.z * wv.x; acc[2][1] += xv.z * wv.y; acc[2][2] += xv.z * wv.z; acc[2][3] += xv.z * wv.w;
            acc[3][0] += xv.w * wv.x; acc[3][1] += xv.w * wv.y; acc[3][2] += xv.w * wv.z; acc[3][3] += xv.w * wv.w;
        }
        __syncthreads();
    }
    #pragma unroll
    for (int i = 0; i < 4; i++) {
        int r = r0 + ty * 4 + i;
        if (r < n) {
            union { __half2 h[2]; float2 f; } u;
            u.h[0] = __floats2half2_rn(acc[i][0], acc[i][1]);
            u.h[1] = __floats2half2_rn(acc[i][2], acc[i][3]);
            *(float2*)&Yh[(size_t)r * HID + tx * 4] = u.f;
        }
    }
}

// ---- fused aggregate (fp16 gather ×norm_out[src]) + norm_in + bias + LN + LeakyReLU ----
__global__ __launch_bounds__(256) void agg_post(const __half* __restrict__ Yh, const int* __restrict__ off,
                                                const int* __restrict__ eidx, const float* __restrict__ nout,
                                                const float* __restrict__ nin,
                                                const float* __restrict__ bias, const float* __restrict__ gam,
                                                const float* __restrict__ bet, float* __restrict__ Xo, int n) {
    int w = threadIdx.x >> 6, lane = threadIdx.x & 63;
    int r = blockIdx.x * 4 + w;
    if (r >= n) return;
    int grp = lane >> 4;
    int s16 = lane & 15;
    int f0 = s16 * 8;
    int s = off[r], e = off[r + 1];

    float af[8];
    #pragma unroll
    for (int i = 0; i < 8; i++) af[i] = 0.f;

    union U { float4 f; __half2 h[4]; };
    for (int j = s; j < e; j += 8) {
        int ia = j + grp, ib = j + 4 + grp;
        bool va = ia < e, vb = ib < e;
        U u1, u2;
        float n1 = 0.f, n2 = 0.f;
        if (va) { int sc = eidx[ia]; u1.f = *(const float4*)&Yh[(size_t)sc * HID + f0]; n1 = nout[sc]; }
        if (vb) { int sc = eidx[ib]; u2.f = *(const float4*)&Yh[(size_t)sc * HID + f0]; n2 = nout[sc]; }
        if (va) {
            #pragma unroll
            for (int k = 0; k < 4; k++) {
                float2 f = __half22float2(u1.h[k]);
                af[2 * k]     = fmaf(n1, f.x, af[2 * k]);
                af[2 * k + 1] = fmaf(n1, f.y, af[2 * k + 1]);
            }
        }
        if (vb) {
            #pragma unroll
            for (int k = 0; k < 4; k++) {
                float2 f = __half22float2(u2.h[k]);
                af[2 * k]     = fmaf(n2, f.x, af[2 * k]);
                af[2 * k + 1] = fmaf(n2, f.y, af[2 * k + 1]);
            }
        }
    }
    #pragma unroll
    for (int i = 0; i < 8; i++) {
        af[i] += __shfl_xor(af[i], 16, 64);
        af[i] += __shfl_xor(af[i], 32, 64);
    }

    float ni = nin[r];
    float4 b0 = *(const float4*)&bias[f0];
    float4 b1 = *(const float4*)&bias[f0 + 4];
    float v[8];
    v[0] = af[0] * ni + b0.x; v[1] = af[1] * ni + b0.y;
    v[2] = af[2] * ni + b0.z; v[3] = af[3] * ni + b0.w;
    v[4] = af[4] * ni + b1.x; v[5] = af[5] * ni + b1.y;
    v[6] = af[6] * ni + b1.z; v[7] = af[7] * ni + b1.w;

    float sum = 0.f;
    #pragma unroll
    for (int i = 0; i < 8; i++) sum += v[i];
    #pragma unroll
    for (int o = 8; o >= 1; o >>= 1) sum += __shfl_xor(sum, o, 64);
    float mu = sum * (1.f / 128.f);

    float d[8], vs = 0.f;
    #pragma unroll
    for (int i = 0; i < 8; i++) { d[i] = v[i] - mu; vs += d[i] * d[i]; }
    #pragma unroll
    for (int o = 8; o >= 1; o >>= 1) vs += __shfl_xor(vs, o, 64);
    float rs = rsqrtf(vs * (1.f / 128.f) + 1e-5f);

    if (grp == 0) {
        float4 g0 = *(const float4*)&gam[f0];
        float4 g1 = *(const float4*)&gam[f0 + 4];
        float4 e0 = *(const float4*)&bet[f0];
        float4 e1 = *(const float4*)&bet[f0 + 4];
        float4 o0, o1;
        o0.x = lrelu(d[0] * rs * g0.x + e0.x);
        o0.y = lrelu(d[1] * rs * g0.y + e0.y);
        o0.z = lrelu(d[2] * rs * g0.z + e0.z);
        o0.w = lrelu(d[3] * rs * g0.w + e0.w);
        o1.x = lrelu(d[4] * rs * g1.x + e1.x);
        o1.y = lrelu(d[5] * rs * g1.y + e1.y);
        o1.z = lrelu(d[6] * rs * g1.z + e1.z);
        o1.w = lrelu(d[7] * rs * g1.w + e1.w);
        *(float4*)&Xo[(size_t)r * HID + f0] = o0;
        *(float4*)&Xo[(size_t)r * HID + f0 + 4] = o1;
    }
}

// ---------------- final projection: Z = norm_out[r] * (X[r] @ W3)   [n,128]x[128,2] ----------------
__global__ __launch_bounds__(256) void mm2(const float* __restrict__ X, const float* __restrict__ W3,
                                           const float* __restrict__ nout, float* __restrict__ Z, int n) {
    int w = threadIdx.x >> 6, lane = threadIdx.x & 63;
    int r = blockIdx.x * 4 + w;
    if (r >= n) return;
    float2 x = *(const float2*)&X[(size_t)r * HID + lane * 2];
    float a0 = x.x * W3[4 * lane + 0] + x.y * W3[4 * lane + 2];
    float a1 = x.x * W3[4 * lane + 1] + x.y * W3[4 * lane + 3];
    #pragma unroll
    for (int o = 32; o >= 1; o >>= 1) {
        a0 += __shfl_xor(a0, o, 64);
        a1 += __shfl_xor(a1, o, 64);
    }
    if (lane == 0) {
        float s = nout[r];
        *(float2*)&Z[r * 2] = make_float2(a0 * s, a1 * s);
    }
}

// ---------------- final aggregation (2 dims), 4-way unrolled ----------------
__global__ void agg3(const float* __restrict__ Z, const int* __restrict__ off,
                     const int* __restrict__ eidx, const float* __restrict__ nin,
                     const float* __restrict__ b3, float* __restrict__ out, int n) {
    int r = blockIdx.x * blockDim.x + threadIdx.x;
    if (r < n) {
        int s = off[r], e = off[r + 1];
        float p0 = 0.f, p1 = 0.f, q0 = 0.f, q1 = 0.f;
        float u0 = 0.f, u1 = 0.f, w0 = 0.f, w1 = 0.f;
        int j = s;
        for (; j + 3 < e; j += 4) {
            float2 v0 = *(const float2*)&Z[eidx[j] * 2];
            float2 v1 = *(const float2*)&Z[eidx[j + 1] * 2];
            float2 v2 = *(const float2*)&Z[eidx[j + 2] * 2];
            float2 v3 = *(const float2*)&Z[eidx[j + 3] * 2];
            p0 += v0.x; p1 += v0.y;
            q0 += v1.x; q1 += v1.y;
            u0 += v2.x; u1 += v2.y;
            w0 += v3.x; w1 += v3.y;
        }
        for (; j < e; ++j) {
            float2 v = *(const float2*)&Z[eidx[j] * 2];
            p0 += v.x; p1 += v.y;
        }
        float a0 = (p0 + q0) + (u0 + w0);
        float a1 = (p1 + q1) + (u1 + w1);
        float ni = nin[r];
        out[r * 2 + 0] = a0 * ni + b3[0];
        out[r * 2 + 1] = a1 * ni + b3[1];
    }
}

extern "C" void kernel_launch(void* const* d_in, const int* in_sizes, int n_in,
                              void* d_out, int out_size, void* d_ws, size_t ws_size,
                              hipStream_t stream) {
    const float* feat = (const float*)d_in[0];
    const int* src = (const int*)d_in[1];
    const int* dst = (const int*)d_in[2];
    const float* W1 = (const float*)d_in[3];
    const float* b1 = (const float*)d_in[4];
    const float* W2 = (const float*)d_in[5];
    const float* b2 = (const float*)d_in[6];
    const float* W3 = (const float*)d_in[7];
    const float* b3 = (const float*)d_in[8];
    const float* g1 = (const float*)d_in[9];
    const float* be1 = (const float*)d_in[10];
    const float* g2 = (const float*)d_in[11];
    const float* be2 = (const float*)d_in[12];
    float* out = (float*)d_out;

    char* p = (char*)d_ws;
    auto carve = [&](size_t bytes) -> char* {
        char* q = p;
        p += (bytes + 255) & ~(size_t)255;
        return q;
    };
    float* norm_out = (float*)carve(NN * 4);
    float* norm_in  = (float*)carve(NN * 4);
    int* deg_out = (int*)carve(NN * 4);
    int* deg_in  = (int*)carve(NN * 4);
    int* off     = (int*)carve((NN + 1) * 4);
    int* bsums   = (int*)carve(64 * 4);
    int* boff    = (int*)carve(64 * 4);
    int* eidx    = (int*)carve((size_t)NE * 4);
    int* rank    = (int*)carve((size_t)NE * 4);
    __half* Yh = (__half*)carve((size_t)NN * HID * 2);
    float* X = (float*)carve((size_t)NN * HID * 4);
    float* Z = (float*)carve((size_t)NN * 2 * 4);

    hipMemsetAsync(deg_out, 0, NN * 4, stream);
    hipMemsetAsync(deg_in, 0, NN * 4, stream);

    // degree counting || GEMM-1 (unnormalized) in one launch
    mega1<<<DEGB + GEMMB, 256, 0, stream>>>(feat, W1, Yh, src, dst, deg_out, deg_in, rank, NN);

    norm_kernel<<<(NN + 255) / 256, 256, 0, stream>>>(deg_out, deg_in, norm_out, norm_in, NN);

    int nb = (NN + 1023) / 1024;  // 49
    scan1<<<nb, 1024, 0, stream>>>(deg_in, off, bsums, NN);
    scan2<<<1, 64, 0, stream>>>(bsums, boff, nb, off + NN);
    scan3<<<nb, 1024, 0, stream>>>(off, boff, NN);
    fill_kernel<<<(NE + 255) / 256, 256, 0, stream>>>(src, dst, off, rank, eidx, NE);

    // layer 1 aggregation (folds norm_out[src])
    agg_post<<<(NN + 3) / 4, 256, 0, stream>>>(Yh, off, eidx, norm_out, norm_in, b1, g1, be1, X, NN);
    // layer 2
    mm128<<<GEMMB, 256, 0, stream>>>(X, W2, Yh, NN);
    agg_post<<<(NN + 3) / 4, 256, 0, stream>>>(Yh, off, eidx, norm_out, norm_in, b2, g2, be2, X, NN);
    // layer 3
    mm2<<<(NN + 3) / 4, 256, 0, stream>>>(X, W3, norm_out, Z, NN);
    agg3<<<(NN + 255) / 256, 256, 0, stream>>>(Z, off, eidx, norm_in, b3, out, NN);
}

// Round 5
// 191.803 us; speedup vs baseline: 2.0162x; 1.2313x over previous
//
#include <hip/hip_runtime.h>
#include <hip/hip_fp16.h>

#define NN 50000
#define NE 800000
#define HID 128
#define DEGB 512
#define GEMMB ((NN + 63) / 64)   // 64 rows per block

typedef _Float16 f16x8 __attribute__((ext_vector_type(8)));
typedef float f32x4 __attribute__((ext_vector_type(4)));

static __device__ __forceinline__ float lrelu(float x) { return x > 0.f ? x : 0.01f * x; }

// ---------------- W converter: fp32 [128][128] -> transposed + pre-swizzled fp16 ----------------
// LDS read will use byte addr (c*256 + kb) ^ ((c&7)<<4). Linear stage copies global[p]->LDS[p],
// so global position p must hold element at unswizzled pos q = p ^ (((p>>8)&7)<<4)  (involution).
__global__ void convW2(const float* __restrict__ W1, const float* __restrict__ W2,
                       _Float16* __restrict__ W1o, _Float16* __restrict__ W2o) {
    int i = blockIdx.x * 256 + threadIdx.x;           // 0..32767
    const float* W = (i < 16384) ? W1 : W2;
    _Float16* O = (i < 16384) ? W1o : W2o;
    int j = i & 16383;
    int p = j * 2;
    int q = p ^ (((p >> 8) & 7) << 4);
    int c = q >> 8;               // output column (0..127)
    int k = (q & 255) >> 1;       // k index (0..127)
    O[j] = (_Float16)W[k * 128 + c];
}

// ---------------- MFMA GEMM body: Y[r0..r0+63][0..127] = A @ W  (fp16 out) ----------------
template <bool AF16>
static __device__ __forceinline__ void gemm_body(const void* __restrict__ A,
                                                 const _Float16* __restrict__ Wsw,
                                                 _Float16* __restrict__ Y, int r0, int n) {
    __shared__ __align__(16) _Float16 Wt[16384];  // 32 KB, swizzled
    int t = threadIdx.x;
    #pragma unroll
    for (int i = 0; i < 8; i++) {
        int idx = t + i * 256;                    // 2048 x 16B chunks
        *(((float4*)Wt) + idx) = ((const float4*)Wsw)[idx];
    }
    int wid = t >> 6, lane = t & 63;
    int kgrp = lane >> 4, l15 = lane & 15;

    // A fragments: lane's row, 8 halves per k-step
    int r = r0 + wid * 16 + l15;
    f16x8 a[4];
    #pragma unroll
    for (int ks = 0; ks < 4; ks++)
        #pragma unroll
        for (int j = 0; j < 8; j++) a[ks][j] = (_Float16)0.f;
    if (r < n) {
        if (AF16) {
            const _Float16* Ah = (const _Float16*)A + (size_t)r * HID + kgrp * 8;
            #pragma unroll
            for (int ks = 0; ks < 4; ks++) a[ks] = *(const f16x8*)(Ah + ks * 32);
        } else {
            const float* Af = (const float*)A + (size_t)r * HID + kgrp * 8;
            #pragma unroll
            for (int ks = 0; ks < 4; ks++) {
                float4 lo = *(const float4*)(Af + ks * 32);
                float4 hi = *(const float4*)(Af + ks * 32 + 4);
                a[ks][0] = (_Float16)lo.x; a[ks][1] = (_Float16)lo.y;
                a[ks][2] = (_Float16)lo.z; a[ks][3] = (_Float16)lo.w;
                a[ks][4] = (_Float16)hi.x; a[ks][5] = (_Float16)hi.y;
                a[ks][6] = (_Float16)hi.z; a[ks][7] = (_Float16)hi.w;
            }
        }
    }
    __syncthreads();

    f32x4 acc[8];
    #pragma unroll
    for (int td = 0; td < 8; td++)
        #pragma unroll
        for (int j = 0; j < 4; j++) acc[td][j] = 0.f;

    const char* base = (const char*)Wt;
    #pragma unroll
    for (int ks = 0; ks < 4; ks++) {
        #pragma unroll
        for (int td = 0; td < 8; td++) {
            int c = td * 16 + l15;
            int addr = ((c << 8) + 64 * ks + 16 * kgrp) ^ ((c & 7) << 4);
            f16x8 b = *(const f16x8*)(base + addr);
            acc[td] = __builtin_amdgcn_mfma_f32_16x16x32_f16(a[ks], b, acc[td], 0, 0, 0);
        }
    }

    int ro = r0 + wid * 16 + kgrp * 4;   // C/D: col = lane&15, row = (lane>>4)*4 + reg
    #pragma unroll
    for (int td = 0; td < 8; td++) {
        #pragma unroll
        for (int reg = 0; reg < 4; reg++) {
            int orow = ro + reg;
            if (orow < n) Y[(size_t)orow * HID + td * 16 + l15] = (_Float16)acc[td][reg];
        }
    }
}

// ---------------- mega1: degree atomics (blocks < DEGB) || MFMA GEMM-1 ----------------
__global__ __launch_bounds__(256) void mega1(const float* __restrict__ feat,
                                             const _Float16* __restrict__ W1sw,
                                             _Float16* __restrict__ Yh,
                                             const int* __restrict__ src, const int* __restrict__ dst,
                                             int* __restrict__ deg_out, int* __restrict__ deg_in,
                                             int* __restrict__ rank, int n) {
    if (blockIdx.x < DEGB) {
        int tid = blockIdx.x * 256 + threadIdx.x;
        for (int e = tid; e < NE; e += DEGB * 256) {
            atomicAdd(&deg_out[src[e]], 1);
            rank[e] = atomicAdd(&deg_in[dst[e]], 1);
        }
        return;
    }
    gemm_body<false>(feat, W1sw, Yh, (blockIdx.x - DEGB) * 64, n);
}

// ---------------- standalone GEMM (layer 2, fp16 A) ----------------
__global__ __launch_bounds__(256) void gemm2(const _Float16* __restrict__ Xh,
                                             const _Float16* __restrict__ W2sw,
                                             _Float16* __restrict__ Yh, int n) {
    gemm_body<true>(Xh, W2sw, Yh, blockIdx.x * 64, n);
}

// ---------------- scan1 fused with norm computation ----------------
__global__ void scan1(const int* __restrict__ deg_in, const int* __restrict__ deg_out,
                      int* __restrict__ excl, int* __restrict__ bsums,
                      float* __restrict__ norm_out, float* __restrict__ norm_in, int n) {
    __shared__ int ws[16];
    int t = threadIdx.x;
    int i = blockIdx.x * 1024 + t;
    int v = (i < n) ? deg_in[i] : 0;
    if (i < n) {
        norm_in[i]  = rsqrtf((float)max(v, 1));
        norm_out[i] = rsqrtf((float)max(deg_out[i], 1));
    }
    int x = v;
    #pragma unroll
    for (int o = 1; o < 64; o <<= 1) {
        int y = __shfl_up(x, o, 64);
        if ((t & 63) >= o) x += y;
    }
    if ((t & 63) == 63) ws[t >> 6] = x;
    __syncthreads();
    if (t < 16) {
        int s = ws[t];
        #pragma unroll
        for (int o = 1; o < 16; o <<= 1) {
            int y = __shfl_up(s, o, 16);
            if (t >= o) s += y;
        }
        ws[t] = s;
    }
    __syncthreads();
    int wid = t >> 6;
    int pre = wid ? ws[wid - 1] : 0;
    if (i < n) excl[i] = pre + x - v;
    if (t == 1023) bsums[blockIdx.x] = ws[15];
}

__global__ void scan2(const int* __restrict__ bsums, int* __restrict__ boff, int nb,
                      int* __restrict__ total_out) {
    int t = threadIdx.x;
    int v = (t < nb) ? bsums[t] : 0;
    int x = v;
    #pragma unroll
    for (int o = 1; o < 64; o <<= 1) {
        int y = __shfl_up(x, o, 64);
        if (t >= o) x += y;
    }
    if (t < nb) boff[t] = x - v;
    if (t == 63) total_out[0] = x;
}

__global__ void scan3(int* __restrict__ off, const int* __restrict__ boff, int n) {
    int i = blockIdx.x * 1024 + threadIdx.x;
    if (i < n) off[i] += boff[blockIdx.x];
}

// ---------------- CSR fill: atomic-free ----------------
__global__ void fill_kernel(const int* __restrict__ src, const int* __restrict__ dst,
                            const int* __restrict__ off, const int* __restrict__ rank,
                            int* __restrict__ eidx, int E) {
    int e = blockIdx.x * blockDim.x + threadIdx.x;
    if (e < E) {
        eidx[off[dst[e]] + rank[e]] = src[e];
    }
}

// ---- fused aggregate (depth-4 fp16 gather * nout[src]) + nin + bias + LN + LeakyReLU ----
// PROJ=false: write fp16 X row.  PROJ=true: project with W3, write Z[r] = nout[r]*(x@W3).
template <bool PROJ>
__global__ __launch_bounds__(256) void agg_post(const __half* __restrict__ Yh, const int* __restrict__ off,
                                                const int* __restrict__ eidx, const float* __restrict__ nout,
                                                const float* __restrict__ nin,
                                                const float* __restrict__ bias, const float* __restrict__ gam,
                                                const float* __restrict__ bet, __half* __restrict__ Xo,
                                                const float* __restrict__ W3, float* __restrict__ Z, int n) {
    int w = threadIdx.x >> 6, lane = threadIdx.x & 63;
    int r = blockIdx.x * 4 + w;
    if (r >= n) return;
    int grp = lane >> 4;
    int f0 = (lane & 15) * 8;
    int s = off[r], e = off[r + 1];

    float af[8];
    #pragma unroll
    for (int i = 0; i < 8; i++) af[i] = 0.f;

    union U { float4 f; __half2 h[4]; };
    for (int j = s; j < e; j += 16) {
        int i0 = j + grp, i1 = i0 + 4, i2 = i0 + 8, i3 = i0 + 12;
        int s0 = (i0 < e) ? eidx[i0] : -1;
        int s1 = (i1 < e) ? eidx[i1] : -1;
        int s2 = (i2 < e) ? eidx[i2] : -1;
        int s3 = (i3 < e) ? eidx[i3] : -1;
        U u0, u1, u2, u3;
        float n0 = 0.f, n1 = 0.f, n2 = 0.f, n3 = 0.f;
        if (s0 >= 0) { u0.f = *(const float4*)&Yh[(size_t)s0 * HID + f0]; n0 = nout[s0]; }
        if (s1 >= 0) { u1.f = *(const float4*)&Yh[(size_t)s1 * HID + f0]; n1 = nout[s1]; }
        if (s2 >= 0) { u2.f = *(const float4*)&Yh[(size_t)s2 * HID + f0]; n2 = nout[s2]; }
        if (s3 >= 0) { u3.f = *(const float4*)&Yh[(size_t)s3 * HID + f0]; n3 = nout[s3]; }
        if (s0 >= 0) {
            #pragma unroll
            for (int k = 0; k < 4; k++) {
                float2 f = __half22float2(u0.h[k]);
                af[2 * k] = fmaf(n0, f.x, af[2 * k]); af[2 * k + 1] = fmaf(n0, f.y, af[2 * k + 1]);
            }
        }
        if (s1 >= 0) {
            #pragma unroll
            for (int k = 0; k < 4; k++) {
                float2 f = __half22float2(u1.h[k]);
                af[2 * k] = fmaf(n1, f.x, af[2 * k]); af[2 * k + 1] = fmaf(n1, f.y, af[2 * k + 1]);
            }
        }
        if (s2 >= 0) {
            #pragma unroll
            for (int k = 0; k < 4; k++) {
                float2 f = __half22float2(u2.h[k]);
                af[2 * k] = fmaf(n2, f.x, af[2 * k]); af[2 * k + 1] = fmaf(n2, f.y, af[2 * k + 1]);
            }
        }
        if (s3 >= 0) {
            #pragma unroll
            for (int k = 0; k < 4; k++) {
                float2 f = __half22float2(u3.h[k]);
                af[2 * k] = fmaf(n3, f.x, af[2 * k]); af[2 * k + 1] = fmaf(n3, f.y, af[2 * k + 1]);
            }
        }
    }
    #pragma unroll
    for (int i = 0; i < 8; i++) {
        af[i] += __shfl_xor(af[i], 16, 64);
        af[i] += __shfl_xor(af[i], 32, 64);
    }

    float ni = nin[r];
    float4 b0 = *(const float4*)&bias[f0];
    float4 b1 = *(const float4*)&bias[f0 + 4];
    float v[8];
    v[0] = af[0] * ni + b0.x; v[1] = af[1] * ni + b0.y;
    v[2] = af[2] * ni + b0.z; v[3] = af[3] * ni + b0.w;
    v[4] = af[4] * ni + b1.x; v[5] = af[5] * ni + b1.y;
    v[6] = af[6] * ni + b1.z; v[7] = af[7] * ni + b1.w;

    float sum = 0.f;
    #pragma unroll
    for (int i = 0; i < 8; i++) sum += v[i];
    #pragma unroll
    for (int o = 8; o >= 1; o >>= 1) sum += __shfl_xor(sum, o, 64);
    float mu = sum * (1.f / 128.f);

    float d[8], vs = 0.f;
    #pragma unroll
    for (int i = 0; i < 8; i++) { d[i] = v[i] - mu; vs += d[i] * d[i]; }
    #pragma unroll
    for (int o = 8; o >= 1; o >>= 1) vs += __shfl_xor(vs, o, 64);
    float rs = rsqrtf(vs * (1.f / 128.f) + 1e-5f);

    float4 g0 = *(const float4*)&gam[f0];
    float4 g1 = *(const float4*)&gam[f0 + 4];
    float4 e0 = *(const float4*)&bet[f0];
    float4 e1 = *(const float4*)&bet[f0 + 4];
    float x[8];
    x[0] = lrelu(d[0] * rs * g0.x + e0.x);
    x[1] = lrelu(d[1] * rs * g0.y + e0.y);
    x[2] = lrelu(d[2] * rs * g0.z + e0.z);
    x[3] = lrelu(d[3] * rs * g0.w + e0.w);
    x[4] = lrelu(d[4] * rs * g1.x + e1.x);
    x[5] = lrelu(d[5] * rs * g1.y + e1.y);
    x[6] = lrelu(d[6] * rs * g1.z + e1.z);
    x[7] = lrelu(d[7] * rs * g1.w + e1.w);

    if (PROJ) {
        float z0 = 0.f, z1 = 0.f;
        #pragma unroll
        for (int i = 0; i < 8; i++) {
            float2 w3 = *(const float2*)&W3[(f0 + i) * 2];
            z0 = fmaf(x[i], w3.x, z0);
            z1 = fmaf(x[i], w3.y, z1);
        }
        #pragma unroll
        for (int o = 8; o >= 1; o >>= 1) {
            z0 += __shfl_xor(z0, o, 64);
            z1 += __shfl_xor(z1, o, 64);
        }
        if (lane == 0) {
            float no = nout[r];
            *(float2*)&Z[r * 2] = make_float2(z0 * no, z1 * no);
        }
    } else {
        if (grp == 0) {
            union { __half2 h[4]; float4 f; } o;
            o.h[0] = __floats2half2_rn(x[0], x[1]);
            o.h[1] = __floats2half2_rn(x[2], x[3]);
            o.h[2] = __floats2half2_rn(x[4], x[5]);
            o.h[3] = __floats2half2_rn(x[6], x[7]);
            *(float4*)&Xo[(size_t)r * HID + f0] = o.f;
        }
    }
}

// ---------------- final aggregation (2 dims), 4-way unrolled ----------------
__global__ void agg3(const float* __restrict__ Z, const int* __restrict__ off,
                     const int* __restrict__ eidx, const float* __restrict__ nin,
                     const float* __restrict__ b3, float* __restrict__ out, int n) {
    int r = blockIdx.x * blockDim.x + threadIdx.x;
    if (r < n) {
        int s = off[r], e = off[r + 1];
        float p0 = 0.f, p1 = 0.f, q0 = 0.f, q1 = 0.f;
        float u0 = 0.f, u1 = 0.f, w0 = 0.f, w1 = 0.f;
        int j = s;
        for (; j + 3 < e; j += 4) {
            float2 v0 = *(const float2*)&Z[eidx[j] * 2];
            float2 v1 = *(const float2*)&Z[eidx[j + 1] * 2];
            float2 v2 = *(const float2*)&Z[eidx[j + 2] * 2];
            float2 v3 = *(const float2*)&Z[eidx[j + 3] * 2];
            p0 += v0.x; p1 += v0.y;
            q0 += v1.x; q1 += v1.y;
            u0 += v2.x; u1 += v2.y;
            w0 += v3.x; w1 += v3.y;
        }
        for (; j < e; ++j) {
            float2 v = *(const float2*)&Z[eidx[j] * 2];
            p0 += v.x; p1 += v.y;
        }
        float a0 = (p0 + q0) + (u0 + w0);
        float a1 = (p1 + q1) + (u1 + w1);
        float ni = nin[r];
        out[r * 2 + 0] = a0 * ni + b3[0];
        out[r * 2 + 1] = a1 * ni + b3[1];
    }
}

extern "C" void kernel_launch(void* const* d_in, const int* in_sizes, int n_in,
                              void* d_out, int out_size, void* d_ws, size_t ws_size,
                              hipStream_t stream) {
    const float* feat = (const float*)d_in[0];
    const int* src = (const int*)d_in[1];
    const int* dst = (const int*)d_in[2];
    const float* W1 = (const float*)d_in[3];
    const float* b1 = (const float*)d_in[4];
    const float* W2 = (const float*)d_in[5];
    const float* b2 = (const float*)d_in[6];
    const float* W3 = (const float*)d_in[7];
    const float* b3 = (const float*)d_in[8];
    const float* g1 = (const float*)d_in[9];
    const float* be1 = (const float*)d_in[10];
    const float* g2 = (const float*)d_in[11];
    const float* be2 = (const float*)d_in[12];
    float* out = (float*)d_out;

    char* p = (char*)d_ws;
    auto carve = [&](size_t bytes) -> char* {
        char* q = p;
        p += (bytes + 255) & ~(size_t)255;
        return q;
    };
    float* norm_out = (float*)carve(NN * 4);
    float* norm_in  = (float*)carve(NN * 4);
    int* deg_out = (int*)carve(NN * 4);
    int* deg_in  = (int*)carve(NN * 4);
    int* off     = (int*)carve((NN + 1) * 4);
    int* bsums   = (int*)carve(64 * 4);
    int* boff    = (int*)carve(64 * 4);
    int* eidx    = (int*)carve((size_t)NE * 4);
    int* rank    = (int*)carve((size_t)NE * 4);
    _Float16* W1sw = (_Float16*)carve(16384 * 2);
    _Float16* W2sw = (_Float16*)carve(16384 * 2);
    _Float16* Yh = (_Float16*)carve((size_t)NN * HID * 2);
    __half* Xh = (__half*)carve((size_t)NN * HID * 2);
    float* Z = (float*)carve((size_t)NN * 2 * 4);

    hipMemsetAsync(deg_out, 0, NN * 4, stream);
    hipMemsetAsync(deg_in, 0, NN * 4, stream);

    convW2<<<128, 256, 0, stream>>>(W1, W2, W1sw, W2sw);

    // degree atomics || MFMA GEMM-1 (unnormalized feat @ W1 -> fp16)
    mega1<<<DEGB + GEMMB, 256, 0, stream>>>(feat, W1sw, Yh, src, dst, deg_out, deg_in, rank, NN);

    int nb = (NN + 1023) / 1024;  // 49
    scan1<<<nb, 1024, 0, stream>>>(deg_in, deg_out, off, bsums, norm_out, norm_in, NN);
    scan2<<<1, 64, 0, stream>>>(bsums, boff, nb, off + NN);
    scan3<<<nb, 1024, 0, stream>>>(off, boff, NN);
    fill_kernel<<<(NE + 255) / 256, 256, 0, stream>>>(src, dst, off, rank, eidx, NE);

    // layer 1 aggregation -> fp16 X
    agg_post<false><<<(NN + 3) / 4, 256, 0, stream>>>((const __half*)Yh, off, eidx, norm_out, norm_in,
                                                      b1, g1, be1, Xh, nullptr, nullptr, NN);
    // layer 2 GEMM (fp16 MFMA)
    gemm2<<<GEMMB, 256, 0, stream>>>((const _Float16*)Xh, W2sw, Yh, NN);
    // layer 2 aggregation fused with layer-3 projection -> Z
    agg_post<true><<<(NN + 3) / 4, 256, 0, stream>>>((const __half*)Yh, off, eidx, norm_out, norm_in,
                                                     b2, g2, be2, nullptr, W3, Z, NN);
    // layer 3 aggregation -> out
    agg3<<<(NN + 255) / 256, 256, 0, stream>>>(Z, off, eidx, norm_in, b3, out, NN);
}